// Round 1
// baseline (37.950 us; speedup 1.0000x reference)
//
#include <hip/hip_runtime.h>

// Aspect-conditional 2-layer MLP:
//   out1 = relu(X[b] @ W1[aid]  + b1[aid])   (768 -> 256)
//   out  = out1 @ W2[aid] + b2[aid]          (256 -> 2)
// One block (256 threads = 4 waves) per sample.
// Wave w covers d in [w*192, w*192+192); lane l owns hidden cols 4l..4l+3
// via float4 loads of W1 (row-major (768,256), so columns are contiguous).

constexpr int D = 768;
constexpr int H = 256;

__global__ __launch_bounds__(256, 4) void aspect_mlp_kernel(
    const float* __restrict__ X,
    const int*   __restrict__ aspect_ids,
    const float* __restrict__ W1_embs,
    const float* __restrict__ b1_embs,
    const float* __restrict__ W2_embs,
    const float* __restrict__ b2_embs,
    float*       __restrict__ out)
{
    __shared__ float xs[D];
    __shared__ float pl[4][H];
    __shared__ float red[4][2];

    const int b = blockIdx.x;
    const int t = threadIdx.x;
    const int w = t >> 6;    // wave 0..3
    const int l = t & 63;    // lane 0..63

    const int aid = aspect_ids[b];

    // stage X row in LDS (768 floats = 192 float4)
    const float4* Xr = reinterpret_cast<const float4*>(X + (size_t)b * D);
    if (t < D / 4) reinterpret_cast<float4*>(xs)[t] = Xr[t];
    __syncthreads();

    // layer 1: each lane accumulates 4 hidden columns over its wave's d-range
    const float4* W1v = reinterpret_cast<const float4*>(
        W1_embs + (size_t)aid * (D * H));

    float4 acc = make_float4(0.f, 0.f, 0.f, 0.f);
    const int d0 = w * (D / 4);                // 192 rows per wave
    #pragma unroll 4
    for (int d = d0; d < d0 + D / 4; ++d) {
        const float  xv = xs[d];               // LDS broadcast
        const float4 wv = W1v[d * (H / 4) + l];
        acc.x = fmaf(xv, wv.x, acc.x);
        acc.y = fmaf(xv, wv.y, acc.y);
        acc.z = fmaf(xv, wv.z, acc.z);
        acc.w = fmaf(xv, wv.w, acc.w);
    }
    reinterpret_cast<float4*>(pl[w])[l] = acc;
    __syncthreads();

    // finish layer 1 (cross-wave sum + bias + relu), thread t owns hidden unit t
    const float o = fmaxf(
        pl[0][t] + pl[1][t] + pl[2][t] + pl[3][t] + b1_embs[aid * H + t], 0.f);

    // layer 2 partials: W2 is (256,2) row-major -> float2 per hidden unit
    const float2 w2 = reinterpret_cast<const float2*>(W2_embs)[aid * H + t];
    float p0 = o * w2.x;
    float p1 = o * w2.y;
    #pragma unroll
    for (int s = 32; s; s >>= 1) {
        p0 += __shfl_xor(p0, s, 64);
        p1 += __shfl_xor(p1, s, 64);
    }
    if (l == 0) { red[w][0] = p0; red[w][1] = p1; }
    __syncthreads();

    if (t == 0) {
        const float2 bias2 = reinterpret_cast<const float2*>(b2_embs)[aid];
        out[b * 2 + 0] = red[0][0] + red[1][0] + red[2][0] + red[3][0] + bias2.x;
        out[b * 2 + 1] = red[0][1] + red[1][1] + red[2][1] + red[3][1] + bias2.y;
    }
}

extern "C" void kernel_launch(void* const* d_in, const int* in_sizes, int n_in,
                              void* d_out, int out_size, void* d_ws, size_t ws_size,
                              hipStream_t stream) {
    const float* X          = (const float*)d_in[0];
    const int*   aspect_ids = (const int*)d_in[1];
    const float* W1_embs    = (const float*)d_in[2];
    const float* b1_embs    = (const float*)d_in[3];
    const float* W2_embs    = (const float*)d_in[4];
    const float* b2_embs    = (const float*)d_in[5];
    float*       out        = (float*)d_out;

    const int B = in_sizes[0] / D;   // 1024
    aspect_mlp_kernel<<<B, 256, 0, stream>>>(
        X, aspect_ids, W1_embs, b1_embs, W2_embs, b2_embs, out);
}